// Round 1
// baseline (699.772 us; speedup 1.0000x reference)
//
#include <hip/hip_runtime.h>
#include <math.h>

#define HWn   3136
#define Cn    256
#define KCPB  49          // 3136/64 k-chunks per batch image
#define NCHUNK 3136       // 64 batches * 49 chunks
#define INV_M (1.0f/200704.0f)
#define EPSc  1e-5f

typedef __attribute__((ext_vector_type(4))) float f32x4;
typedef __attribute__((ext_vector_type(8))) short s16x8;
typedef __attribute__((ext_vector_type(4))) unsigned short u16x4;

static __device__ __forceinline__ unsigned short f2bf(float f) {
  unsigned int u = __builtin_bit_cast(unsigned int, f);
  u = (u + 0x7fffu + ((u >> 16) & 1u)) >> 16;   // RNE
  return (unsigned short)u;
}
static __device__ __forceinline__ float bf2f(unsigned short h) {
  unsigned int u = ((unsigned int)h) << 16;
  return __builtin_bit_cast(float, u);
}

// ---------------------------------------------------------------------------
// Kernel 1: partial Gram (raw, uncentered) + partial channel sums, one X pass.
// Each workgroup (1024 thr = 16 waves) owns a set of (b, k-chunk) chunks and
// accumulates a full 256x256 partial Gram in MFMA accumulators.
// LDS tile: [256 ch][64 k] bf16, XOR-swizzled (^ (c&7)<<4 bytes).
// Wave w computes rows 16w..16w+15; frag[j] doubles as A (j==w) and B operand.
// ---------------------------------------------------------------------------
__global__ __launch_bounds__(1024) void k_gram(const float* __restrict__ X,
                                               float* __restrict__ Gp,
                                               float* __restrict__ Sp,
                                               int nparts) {
  __shared__ __align__(16) unsigned short lds[256 * 64];
  const int t = threadIdx.x, p = blockIdx.x;
  const int w = t >> 6, l = t & 63, a = l & 15, g = l >> 4;
  const int swzA = (a & 7) << 3;          // ushort-unit swizzle (16B granules)
  const int ct = t & 255, qq = t >> 8;

  f32x4 acc[16];
#pragma unroll
  for (int j = 0; j < 16; ++j) acc[j] = (f32x4){0.f, 0.f, 0.f, 0.f};
  float suml = 0.f;

  const int start = (int)(((long)NCHUNK * p) / nparts);
  const int end   = (int)(((long)NCHUNK * (p + 1)) / nparts);

  for (int ch = start; ch < end; ++ch) {
    const int b = ch / KCPB, kc = ch % KCPB;
    const float* xb = X + (long)b * Cn * HWn + kc * 64;
    // ---- stage [256][64] fp32 -> bf16 LDS (swizzled) ----
#pragma unroll
    for (int p4 = 0; p4 < 4; ++p4) {
      const int idx = p4 * 1024 + t;
      const int c = idx >> 4, sg = idx & 15;
      const float4 v = *(const float4*)(xb + (long)c * HWn + sg * 4);
      u16x4 h;
      h.x = f2bf(v.x); h.y = f2bf(v.y); h.z = f2bf(v.z); h.w = f2bf(v.w);
      const int ui = (c * 64 + sg * 4) ^ ((c & 7) << 3);
      *(u16x4*)(lds + ui) = h;
    }
    __syncthreads();
    // ---- channel sums (from bf16 tile; error ~1e-5 on mean, negligible) ----
    {
      const int i0 = ct * 64 + qq * 16;
      const int sw = (ct & 7) << 3;
      const s16x8 u0 = *(const s16x8*)(lds + (i0 ^ sw));
      const s16x8 u1 = *(const s16x8*)(lds + ((i0 + 8) ^ sw));
#pragma unroll
      for (int i = 0; i < 8; ++i) {
        suml += bf2f((unsigned short)u0[i]);
        suml += bf2f((unsigned short)u1[i]);
      }
    }
    // ---- MFMA: acc[j] += frag[w] * frag[j]  (Gram is operand-order-proof) --
#pragma unroll
    for (int kk = 0; kk < 64; kk += 32) {
      const s16x8 fw = *(const s16x8*)(lds + (((w * 16 + a) * 64 + kk + g * 8) ^ swzA));
#pragma unroll
      for (int j = 0; j < 16; ++j) {
        const s16x8 fj = *(const s16x8*)(lds + (((j * 16 + a) * 64 + kk + g * 8) ^ swzA));
        acc[j] = __builtin_amdgcn_mfma_f32_16x16x32_bf16(fw, fj, acc[j], 0, 0, 0);
      }
    }
    __syncthreads();
  }
  // ---- write partial Gram: D layout col=lane&15, row=(lane>>4)*4+reg ----
  float* gout = Gp + (long)p * 65536;
#pragma unroll
  for (int j = 0; j < 16; ++j)
#pragma unroll
    for (int r = 0; r < 4; ++r)
      gout[(16 * w + 4 * g + r) * 256 + 16 * j + a] = acc[j][r];
  Sp[(long)p * 1024 + qq * 256 + ct] = suml;
}

// ---------------------------------------------------------------------------
// Kernel 2: reduce partials -> Sigma (with mean correction + eps*I), P0 = I.
// ---------------------------------------------------------------------------
__global__ void k_reduce(const float* __restrict__ Gp, const float* __restrict__ Sp,
                         float* __restrict__ Sigma, float* __restrict__ P0,
                         float* __restrict__ meanv, int nparts) {
  __shared__ float lm[256];
  const int j = blockIdx.x, c = threadIdx.x;
  float s = 0.f;
  for (int p = 0; p < nparts; ++p) {
    const float* sp = Sp + (long)p * 1024 + c;
    s += sp[0] + sp[256] + sp[512] + sp[768];
  }
  const float mc = s * INV_M;
  lm[c] = mc;
  __syncthreads();
  const float mj = lm[j];
  float gsum = 0.f;
  for (int p = 0; p < nparts; ++p) gsum += Gp[(long)p * 65536 + j * 256 + c];
  const float sig = gsum * INV_M - mj * mc + ((j == c) ? EPSc : 0.f);
  Sigma[j * 256 + c] = sig;
  P0[j * 256 + c] = (j == c) ? 1.f : 0.f;
  if (j == 0) meanv[c] = mc;
}

// ---------------------------------------------------------------------------
// Kernel 3: rTr = 1/trace(Sigma), sqrt(rTr).
// ---------------------------------------------------------------------------
__global__ void k_prep(const float* __restrict__ Sigma, float* __restrict__ scal) {
  __shared__ float red[256];
  const int c = threadIdx.x;
  red[c] = Sigma[c * 257];
  __syncthreads();
  for (int st = 128; st > 0; st >>= 1) {
    if (c < st) red[c] += red[c + st];
    __syncthreads();
  }
  if (c == 0) {
    const float rTr = 1.0f / red[0];
    scal[0] = rTr;
    scal[1] = sqrtf(rTr);
  }
}

// ---------------------------------------------------------------------------
// Kernel 4 (x10): one Newton-Schulz step, fp32.
// Block = 8-row panel: Pd = 1.5*P - 0.5*rTr*(Panel*P*P*Sigma).
// ---------------------------------------------------------------------------
__global__ void k_ns(const float* __restrict__ Ps, float* __restrict__ Pd,
                     const float* __restrict__ Sig, const float* __restrict__ scal) {
  __shared__ float Rw[8][256];
  __shared__ float Tw[8][256];
  const int r0 = blockIdx.x * 8, c = threadIdx.x;
#pragma unroll
  for (int r = 0; r < 8; ++r) Rw[r][c] = Ps[(r0 + r) * 256 + c];
  __syncthreads();
  float pr[8];
#pragma unroll
  for (int r = 0; r < 8; ++r) pr[r] = Rw[r][c];

  float t1[8];
#pragma unroll
  for (int r = 0; r < 8; ++r) t1[r] = 0.f;
  for (int k = 0; k < 256; ++k) {
    const float pv = Ps[k * 256 + c];
#pragma unroll
    for (int r = 0; r < 8; ++r) t1[r] += Rw[r][k] * pv;
  }
#pragma unroll
  for (int r = 0; r < 8; ++r) Tw[r][c] = t1[r];
  __syncthreads();

  float t2[8];
#pragma unroll
  for (int r = 0; r < 8; ++r) t2[r] = 0.f;
  for (int k = 0; k < 256; ++k) {
    const float pv = Ps[k * 256 + c];
#pragma unroll
    for (int r = 0; r < 8; ++r) t2[r] += Tw[r][k] * pv;
  }
#pragma unroll
  for (int r = 0; r < 8; ++r) Rw[r][c] = t2[r];   // P^3 panel (Rw reads all done)
  __syncthreads();

  float t3[8];
#pragma unroll
  for (int r = 0; r < 8; ++r) t3[r] = 0.f;
  for (int k = 0; k < 256; ++k) {
    const float sv = Sig[k * 256 + c];
#pragma unroll
    for (int r = 0; r < 8; ++r) t3[r] += Rw[r][k] * sv;
  }
  const float rTr = scal[0];
#pragma unroll
  for (int r = 0; r < 8; ++r)
    Pd[(r0 + r) * 256 + c] = 1.5f * pr[r] - 0.5f * rTr * t3[r];
}

// ---------------------------------------------------------------------------
// Kernel 5: A = sqrt(rTr) * (rot * P) -> bf16; bias = A * mean.
// ---------------------------------------------------------------------------
__global__ void k_makeA(const float* __restrict__ rot, const float* __restrict__ P,
                        const float* __restrict__ scal, const float* __restrict__ meanv,
                        unsigned short* __restrict__ Abf, float* __restrict__ bias) {
  __shared__ float Rw[8][256];
  __shared__ float Tw[8][256];
  const int r0 = blockIdx.x * 8, c = threadIdx.x;
#pragma unroll
  for (int r = 0; r < 8; ++r) Rw[r][c] = rot[(r0 + r) * 256 + c];
  __syncthreads();
  float t[8];
#pragma unroll
  for (int r = 0; r < 8; ++r) t[r] = 0.f;
  for (int k = 0; k < 256; ++k) {
    const float pv = P[k * 256 + c];
#pragma unroll
    for (int r = 0; r < 8; ++r) t[r] += Rw[r][k] * pv;
  }
  const float s = scal[1];
  const float mc = meanv[c];
#pragma unroll
  for (int r = 0; r < 8; ++r) {
    const float av = t[r] * s;
    Abf[(r0 + r) * 256 + c] = f2bf(av);
    Tw[r][c] = av * mc;
  }
  __syncthreads();
  for (int st = 128; st > 0; st >>= 1) {
    if (c < st) {
#pragma unroll
      for (int r = 0; r < 8; ++r) Tw[r][c] += Tw[r][c + st];
    }
    __syncthreads();
  }
  if (c == 0) {
#pragma unroll
    for (int r = 0; r < 8; ++r) bias[r0 + r] = Tw[r][0];
  }
}

// ---------------------------------------------------------------------------
// Kernel 6: out = A*x - bias, per (b, 64-col s-chunk). Full K=256 staged in
// LDS as x^T [64 s][256 c] bf16 (XOR-swizzled). A frags read from global (L2).
// ---------------------------------------------------------------------------
__global__ __launch_bounds__(1024) void k_apply(const float* __restrict__ X,
                                                const unsigned short* __restrict__ Abf,
                                                const float* __restrict__ bias,
                                                float* __restrict__ out) {
  __shared__ __align__(16) unsigned short lds[64 * 256];
  const int bid = blockIdx.x;
  const int b = bid / KCPB, sc = bid % KCPB, s0 = sc * 64;
  const int t = threadIdx.x, w = t >> 6, l = t & 63, a = l & 15, g = l >> 4;

  // ---- stage x^T chunk: wave w, pass p4 -> channels 4*(p4*16+w).. ; lane=s --
#pragma unroll
  for (int p4 = 0; p4 < 4; ++p4) {
    const int c4 = p4 * 16 + w;
    const float* xp = X + ((long)b * Cn + c4 * 4) * HWn + s0 + l;
    u16x4 h;
    h.x = f2bf(xp[0]);
    h.y = f2bf(xp[HWn]);
    h.z = f2bf(xp[2 * HWn]);
    h.w = f2bf(xp[3 * HWn]);
    const int ui = (l * 256 + c4 * 4) ^ ((l & 7) << 3);
    *(u16x4*)(lds + ui) = h;
  }
  __syncthreads();

  f32x4 acc[4];
#pragma unroll
  for (int st = 0; st < 4; ++st) acc[st] = (f32x4){0.f, 0.f, 0.f, 0.f};

#pragma unroll
  for (int kk = 0; kk < 256; kk += 32) {
    const s16x8 af = *(const s16x8*)(Abf + (16 * w + a) * 256 + kk + g * 8);
#pragma unroll
    for (int st = 0; st < 4; ++st) {
      const s16x8 bf = *(const s16x8*)(lds + (((st * 16 + a) * 256 + kk + g * 8) ^ ((a & 7) << 3)));
      acc[st] = __builtin_amdgcn_mfma_f32_16x16x32_bf16(af, bf, acc[st], 0, 0, 0);
    }
  }

#pragma unroll
  for (int r = 0; r < 4; ++r) {
    const int d = 16 * w + 4 * g + r;
    const float bd = bias[d];
    float* op = out + ((long)b * Cn + d) * HWn + s0 + a;
#pragma unroll
    for (int st = 0; st < 4; ++st) op[st * 16] = acc[st][r] - bd;
  }
}

// ---------------------------------------------------------------------------
extern "C" void kernel_launch(void* const* d_in, const int* in_sizes, int n_in,
                              void* d_out, int out_size, void* d_ws, size_t ws_size,
                              hipStream_t stream) {
  const float* X = (const float*)d_in[0];
  const float* rot = (const float*)d_in[1];
  float* out = (float*)d_out;

  // workspace layout (all offsets 16B aligned)
  auto need = [](int np) -> size_t {
    return (size_t)4 * ((size_t)np * 65536 + (size_t)np * 1024 + 3 * 65536 + 256 + 16 + 256)
         + (size_t)2 * 65536;
  };
  int nparts = 256;
  while (nparts > 1 && need(nparts) > ws_size) nparts >>= 1;

  float* w = (float*)d_ws;
  float* Gp = w;      w += (size_t)nparts * 65536;
  float* Sp = w;      w += (size_t)nparts * 1024;
  float* Sigma = w;   w += 65536;
  float* P0 = w;      w += 65536;
  float* P1 = w;      w += 65536;
  float* meanv = w;   w += 256;
  float* scal = w;    w += 16;
  float* bias = w;    w += 256;
  unsigned short* Abf = (unsigned short*)w;

  k_gram<<<dim3(nparts), dim3(1024), 0, stream>>>(X, Gp, Sp, nparts);
  k_reduce<<<dim3(256), dim3(256), 0, stream>>>(Gp, Sp, Sigma, P0, meanv, nparts);
  k_prep<<<dim3(1), dim3(256), 0, stream>>>(Sigma, scal);
  float* ps = P0;
  float* pd = P1;
  for (int i = 0; i < 10; ++i) {
    k_ns<<<dim3(32), dim3(256), 0, stream>>>(ps, pd, Sigma, scal);
    float* tmp = ps; ps = pd; pd = tmp;
  }
  k_makeA<<<dim3(32), dim3(256), 0, stream>>>(rot, ps, scal, meanv, Abf, bias);
  k_apply<<<dim3(64 * KCPB), dim3(1024), 0, stream>>>(X, Abf, bias, out);
}

// Round 2
// 360.106 us; speedup vs baseline: 1.9432x; 1.9432x over previous
//
#include <hip/hip_runtime.h>
#include <math.h>

#define HWn   3136
#define Cn    256
#define KCPB  49          // 3136/64 k-chunks per batch image
#define NCHUNK 3136       // 64 batches * 49 chunks
#define INV_M (1.0f/200704.0f)
#define EPSc  1e-5f

typedef __attribute__((ext_vector_type(4))) float f32x4;
typedef __attribute__((ext_vector_type(8))) short s16x8;
typedef __attribute__((ext_vector_type(4))) unsigned short u16x4;

static __device__ __forceinline__ unsigned short f2bf(float f) {
  unsigned int u = __builtin_bit_cast(unsigned int, f);
  u = (u + 0x7fffu + ((u >> 16) & 1u)) >> 16;   // RNE
  return (unsigned short)u;
}
static __device__ __forceinline__ float bf2f(unsigned short h) {
  unsigned int u = ((unsigned int)h) << 16;
  return __builtin_bit_cast(float, u);
}

// ---------------------------------------------------------------------------
// Kernel 1: partial Gram (raw, uncentered) + channel-sum atomics, one X pass.
// ---------------------------------------------------------------------------
__global__ __launch_bounds__(1024) void k_gram(const float* __restrict__ X,
                                               float* __restrict__ Gp,
                                               float* __restrict__ meansum,
                                               int nparts) {
  __shared__ __align__(16) unsigned short lds[256 * 64];
  const int t = threadIdx.x, p = blockIdx.x;
  const int w = t >> 6, l = t & 63, a = l & 15, g = l >> 4;
  const int swzA = (a & 7) << 3;          // ushort-unit swizzle (16B granules)
  const int ct = t & 255, qq = t >> 8;

  f32x4 acc[16];
#pragma unroll
  for (int j = 0; j < 16; ++j) acc[j] = (f32x4){0.f, 0.f, 0.f, 0.f};
  float suml = 0.f;

  const int start = (int)(((long)NCHUNK * p) / nparts);
  const int end   = (int)(((long)NCHUNK * (p + 1)) / nparts);

  for (int ch = start; ch < end; ++ch) {
    const int b = ch / KCPB, kc = ch % KCPB;
    const float* xb = X + (long)b * Cn * HWn + kc * 64;
    // ---- stage [256][64] fp32 -> bf16 LDS (swizzled) ----
#pragma unroll
    for (int p4 = 0; p4 < 4; ++p4) {
      const int idx = p4 * 1024 + t;
      const int c = idx >> 4, sg = idx & 15;
      const float4 v = *(const float4*)(xb + (long)c * HWn + sg * 4);
      u16x4 h;
      h.x = f2bf(v.x); h.y = f2bf(v.y); h.z = f2bf(v.z); h.w = f2bf(v.w);
      const int ui = (c * 64 + sg * 4) ^ ((c & 7) << 3);
      *(u16x4*)(lds + ui) = h;
    }
    __syncthreads();
    // ---- channel sums from bf16 tile ----
    {
      const int i0 = ct * 64 + qq * 16;
      const int sw = (ct & 7) << 3;
      const s16x8 u0 = *(const s16x8*)(lds + (i0 ^ sw));
      const s16x8 u1 = *(const s16x8*)(lds + ((i0 + 8) ^ sw));
#pragma unroll
      for (int i = 0; i < 8; ++i) {
        suml += bf2f((unsigned short)u0[i]);
        suml += bf2f((unsigned short)u1[i]);
      }
    }
    // ---- MFMA: acc[j] += frag[w] * frag[j] ----
#pragma unroll
    for (int kk = 0; kk < 64; kk += 32) {
      const s16x8 fw = *(const s16x8*)(lds + (((w * 16 + a) * 64 + kk + g * 8) ^ swzA));
#pragma unroll
      for (int j = 0; j < 16; ++j) {
        const s16x8 fj = *(const s16x8*)(lds + (((j * 16 + a) * 64 + kk + g * 8) ^ swzA));
        acc[j] = __builtin_amdgcn_mfma_f32_16x16x32_bf16(fw, fj, acc[j], 0, 0, 0);
      }
    }
    __syncthreads();
  }
  // ---- write partial Gram ----
  float* gout = Gp + (long)p * 65536;
#pragma unroll
  for (int j = 0; j < 16; ++j)
#pragma unroll
    for (int r = 0; r < 4; ++r)
      gout[(16 * w + 4 * g + r) * 256 + 16 * j + a] = acc[j][r];
  // ---- channel-sum block reduce + atomic ----
  float* lf = (float*)lds;
  lf[t] = suml;
  __syncthreads();
  if (t < 256) {
    const float s = lf[t] + lf[t + 256] + lf[t + 512] + lf[t + 768];
    atomicAdd(&meansum[t], s);
  }
}

// ---------------------------------------------------------------------------
// Kernel 2: reduce partials -> Sigma row per block; P0 = I; trace atomic.
// 256 blocks x 1024 threads; coalesced 1KB slab per p-iteration; split-p x4.
// ---------------------------------------------------------------------------
__global__ __launch_bounds__(1024) void k_reduce(const float* __restrict__ Gp,
                                                 const float* __restrict__ meansum,
                                                 float* __restrict__ Sigma,
                                                 float* __restrict__ P0,
                                                 float* __restrict__ scal,
                                                 int nparts) {
  __shared__ float red[4][256];
  const int t = threadIdx.x, c = t & 255, g = t >> 8, j = blockIdx.x;
  const long e = (long)j * 256 + c;
  const int p0 = (nparts * g) >> 2, p1 = (nparts * (g + 1)) >> 2;
  const float* gp = Gp + (long)p0 * 65536 + e;
  const int np = p1 - p0;
  float s0 = 0.f, s1 = 0.f, s2 = 0.f, s3 = 0.f;
  int p = 0;
#pragma unroll 2
  for (; p + 4 <= np; p += 4) {
    s0 += gp[(long)(p + 0) * 65536];
    s1 += gp[(long)(p + 1) * 65536];
    s2 += gp[(long)(p + 2) * 65536];
    s3 += gp[(long)(p + 3) * 65536];
  }
  for (; p < np; ++p) s0 += gp[(long)p * 65536];
  red[g][c] = (s0 + s1) + (s2 + s3);
  __syncthreads();
  if (g == 0) {
    const float tot = red[0][c] + red[1][c] + red[2][c] + red[3][c];
    const float mc = meansum[c] * INV_M;
    const float mj = meansum[j] * INV_M;
    const float sig = tot * INV_M - mj * mc + ((j == c) ? EPSc : 0.f);
    Sigma[e] = sig;
    if (c == j) atomicAdd(scal, sig);
  } else if (g == 1) {
    P0[e] = (j == c) ? 1.f : 0.f;
  }
}

// ---------------------------------------------------------------------------
// Kernel 3 (x10): one Newton-Schulz step, fp32, register-tiled 4x4.
// 64 blocks (4 rows each) x 256 threads (64 col-threads x split-K 4).
// Per k: 1 ds_read_b128 (uniform A) + 1 global float4 (B) + 16 FMA.
// ---------------------------------------------------------------------------
__global__ __launch_bounds__(256) void k_ns(const float* __restrict__ Ps,
                                            float* __restrict__ Pd,
                                            const float* __restrict__ Sig,
                                            const float* __restrict__ scal) {
  __shared__ __align__(16) float PT[256][4];      // transposed A-panel [k][r]
  __shared__ __align__(16) float red[4][4][256];  // split-K partials
  const int t = threadIdx.x;
  const int ct = t & 63, kh = t >> 6;
  const int c0 = ct * 4, k0 = kh * 64;
  const int r0 = blockIdx.x * 4;

  // stage original panel transposed
#pragma unroll
  for (int j = 0; j < 4; ++j) PT[t][j] = Ps[(r0 + j) * 256 + t];
  __syncthreads();

  f32x4 acc[4];

#define NS_PHASE(BPTR)                                                        \
  {                                                                           \
    _Pragma("unroll")                                                         \
    for (int i = 0; i < 4; ++i) acc[i] = (f32x4){0.f, 0.f, 0.f, 0.f};         \
    const float* Bb = (BPTR) + (long)k0 * 256 + c0;                           \
    _Pragma("unroll 4")                                                       \
    for (int kk = 0; kk < 64; ++kk) {                                         \
      const f32x4 a = *(const f32x4*)&PT[k0 + kk][0];                         \
      const float4 b = *(const float4*)(Bb + (long)kk * 256);                 \
      _Pragma("unroll")                                                       \
      for (int i = 0; i < 4; ++i) {                                           \
        acc[i][0] += a[i] * b.x; acc[i][1] += a[i] * b.y;                     \
        acc[i][2] += a[i] * b.z; acc[i][3] += a[i] * b.w;                     \
      }                                                                       \
    }                                                                         \
    _Pragma("unroll")                                                         \
    for (int i = 0; i < 4; ++i) *(f32x4*)&red[kh][i][c0] = acc[i];            \
    __syncthreads();                                                          \
  }

#define NS_COMBINE()                                                          \
  {                                                                           \
    _Pragma("unroll")                                                         \
    for (int j = 0; j < 4; ++j)                                               \
      PT[t][j] = (red[0][j][t] + red[1][j][t]) + (red[2][j][t] + red[3][j][t]); \
    __syncthreads();                                                          \
  }

  NS_PHASE(Ps);    // t1 = panel(P) * P
  NS_COMBINE();
  NS_PHASE(Ps);    // t2 = t1 * P
  NS_COMBINE();
  NS_PHASE(Sig);   // t3 = t2 * Sigma
  // epilogue: Pd = 1.5 P - 0.5 rTr * t3
  const float rTr = 1.0f / scal[0];
#pragma unroll
  for (int j = 0; j < 4; ++j) {
    const float t3 = (red[0][j][t] + red[1][j][t]) + (red[2][j][t] + red[3][j][t]);
    const float pr = Ps[(r0 + j) * 256 + t];
    Pd[(r0 + j) * 256 + t] = 1.5f * pr - 0.5f * rTr * t3;
  }
#undef NS_PHASE
#undef NS_COMBINE
}

// ---------------------------------------------------------------------------
// Kernel 4: A = sqrt(rTr) * (rot * P) -> bf16; bias = A * mean.
// ---------------------------------------------------------------------------
__global__ void k_makeA(const float* __restrict__ rot, const float* __restrict__ P,
                        const float* __restrict__ scal, const float* __restrict__ meansum,
                        unsigned short* __restrict__ Abf, float* __restrict__ bias) {
  __shared__ float Rw[8][256];
  __shared__ float Tw[8][256];
  const int r0 = blockIdx.x * 8, c = threadIdx.x;
#pragma unroll
  for (int r = 0; r < 8; ++r) Rw[r][c] = rot[(r0 + r) * 256 + c];
  __syncthreads();
  float t[8];
#pragma unroll
  for (int r = 0; r < 8; ++r) t[r] = 0.f;
  for (int k = 0; k < 256; ++k) {
    const float pv = P[k * 256 + c];
#pragma unroll
    for (int r = 0; r < 8; ++r) t[r] += Rw[r][k] * pv;
  }
  const float s = sqrtf(1.0f / scal[0]);
  const float mc = meansum[c] * INV_M;
#pragma unroll
  for (int r = 0; r < 8; ++r) {
    const float av = t[r] * s;
    Abf[(r0 + r) * 256 + c] = f2bf(av);
    Tw[r][c] = av * mc;
  }
  __syncthreads();
  for (int st = 128; st > 0; st >>= 1) {
    if (c < st) {
#pragma unroll
      for (int r = 0; r < 8; ++r) Tw[r][c] += Tw[r][c + st];
    }
    __syncthreads();
  }
  if (c == 0) {
#pragma unroll
    for (int r = 0; r < 8; ++r) bias[r0 + r] = Tw[r][0];
  }
}

// ---------------------------------------------------------------------------
// Kernel 5: out = A*x - bias, per (b, 64-col s-chunk).
// ---------------------------------------------------------------------------
__global__ __launch_bounds__(1024) void k_apply(const float* __restrict__ X,
                                                const unsigned short* __restrict__ Abf,
                                                const float* __restrict__ bias,
                                                float* __restrict__ out) {
  __shared__ __align__(16) unsigned short lds[64 * 256];
  const int bid = blockIdx.x;
  const int b = bid / KCPB, sc = bid % KCPB, s0 = sc * 64;
  const int t = threadIdx.x, w = t >> 6, l = t & 63, a = l & 15, g = l >> 4;

#pragma unroll
  for (int p4 = 0; p4 < 4; ++p4) {
    const int c4 = p4 * 16 + w;
    const float* xp = X + ((long)b * Cn + c4 * 4) * HWn + s0 + l;
    u16x4 h;
    h.x = f2bf(xp[0]);
    h.y = f2bf(xp[HWn]);
    h.z = f2bf(xp[2 * HWn]);
    h.w = f2bf(xp[3 * HWn]);
    const int ui = (l * 256 + c4 * 4) ^ ((l & 7) << 3);
    *(u16x4*)(lds + ui) = h;
  }
  __syncthreads();

  f32x4 acc[4];
#pragma unroll
  for (int st = 0; st < 4; ++st) acc[st] = (f32x4){0.f, 0.f, 0.f, 0.f};

#pragma unroll
  for (int kk = 0; kk < 256; kk += 32) {
    const s16x8 af = *(const s16x8*)(Abf + (16 * w + a) * 256 + kk + g * 8);
#pragma unroll
    for (int st = 0; st < 4; ++st) {
      const s16x8 bf = *(const s16x8*)(lds + (((st * 16 + a) * 256 + kk + g * 8) ^ ((a & 7) << 3)));
      acc[st] = __builtin_amdgcn_mfma_f32_16x16x32_bf16(af, bf, acc[st], 0, 0, 0);
    }
  }

#pragma unroll
  for (int r = 0; r < 4; ++r) {
    const int d = 16 * w + 4 * g + r;
    const float bd = bias[d];
    float* op = out + ((long)b * Cn + d) * HWn + s0 + a;
#pragma unroll
    for (int st = 0; st < 4; ++st) op[st * 16] = acc[st][r] - bd;
  }
}

// ---------------------------------------------------------------------------
extern "C" void kernel_launch(void* const* d_in, const int* in_sizes, int n_in,
                              void* d_out, int out_size, void* d_ws, size_t ws_size,
                              hipStream_t stream) {
  const float* X = (const float*)d_in[0];
  const float* rot = (const float*)d_in[1];
  float* out = (float*)d_out;

  auto need = [](int np) -> size_t {
    return (size_t)4 * ((size_t)np * 65536 + 3 * 65536 + 256 + 16 + 256)
         + (size_t)2 * 65536;
  };
  int nparts = 256;
  while (nparts > 4 && need(nparts) > ws_size) nparts >>= 1;

  float* w = (float*)d_ws;
  float* Gp = w;       w += (size_t)nparts * 65536;
  float* Sigma = w;    w += 65536;
  float* P0 = w;       w += 65536;
  float* P1 = w;       w += 65536;
  float* meansum = w;  w += 256;
  float* scal = w;     w += 16;
  float* bias = w;     w += 256;
  unsigned short* Abf = (unsigned short*)w;

  // zero the atomic accumulators (meansum + scal are contiguous)
  hipMemsetAsync(meansum, 0, (256 + 16) * sizeof(float), stream);

  k_gram<<<dim3(nparts), dim3(1024), 0, stream>>>(X, Gp, meansum, nparts);
  k_reduce<<<dim3(256), dim3(1024), 0, stream>>>(Gp, meansum, Sigma, P0, scal, nparts);
  float* ps = P0;
  float* pd = P1;
  for (int i = 0; i < 10; ++i) {
    k_ns<<<dim3(64), dim3(256), 0, stream>>>(ps, pd, Sigma, scal);
    float* tmp = ps; ps = pd; pd = tmp;
  }
  k_makeA<<<dim3(32), dim3(256), 0, stream>>>(rot, ps, scal, meansum, Abf, bias);
  k_apply<<<dim3(64 * KCPB), dim3(1024), 0, stream>>>(X, Abf, bias, out);
}

// Round 3
// 303.974 us; speedup vs baseline: 2.3021x; 1.1847x over previous
//
#include <hip/hip_runtime.h>
#include <math.h>

#define HWn   3136
#define Cn    256
#define KCPB  49          // 3136/64 k-chunks per batch image
#define NCHUNK 3136       // 64 batches * 49 chunks
#define INV_M (1.0f/200704.0f)
#define EPSc  1e-5f

typedef __attribute__((ext_vector_type(4))) float f32x4;
typedef __attribute__((ext_vector_type(8))) short s16x8;
typedef __attribute__((ext_vector_type(4))) unsigned short u16x4;

static __device__ __forceinline__ unsigned short f2bf(float f) {
  unsigned int u = __builtin_bit_cast(unsigned int, f);
  u = (u + 0x7fffu + ((u >> 16) & 1u)) >> 16;   // RNE
  return (unsigned short)u;
}

// ---------------------------------------------------------------------------
// Kernel 1: partial Gram (raw, uncentered) + channel-sum atomics, one X pass.
// Double-buffered LDS, T14 split (loads -> MFMA -> cvt+write -> barrier).
// Channel sums accumulated from fp32 stage registers (no LDS re-read pass).
// ---------------------------------------------------------------------------
__global__ __launch_bounds__(1024) void k_gram(const float* __restrict__ X,
                                               float* __restrict__ Gp,
                                               float* __restrict__ meansum,
                                               int nparts) {
  __shared__ __align__(16) unsigned short lds[2][256 * 64];
  const int t = threadIdx.x, p = blockIdx.x;
  const int w = t >> 6, l = t & 63, a = l & 15, g = l >> 4;
  const int swzA = (a & 7) << 3;
  const int crow = t >> 4, sg = t & 15;      // staging: c = p4*64 + crow, s-offs = sg*4

  f32x4 acc[16];
#pragma unroll
  for (int j = 0; j < 16; ++j) acc[j] = (f32x4){0.f, 0.f, 0.f, 0.f};
  float sum4[4] = {0.f, 0.f, 0.f, 0.f};
  float vx[16];

  const int start = (int)(((long)NCHUNK * p) / nparts);
  const int end   = (int)(((long)NCHUNK * (p + 1)) / nparts);

#define G_LOADS(CH)                                                           \
  {                                                                           \
    const int b_ = (CH) / KCPB, kc_ = (CH) % KCPB;                            \
    const float* xb_ = X + (long)b_ * Cn * HWn + kc_ * 64;                    \
    _Pragma("unroll")                                                         \
    for (int p4 = 0; p4 < 4; ++p4) {                                          \
      const float4 v = *(const float4*)(xb_ + (long)(p4 * 64 + crow) * HWn + sg * 4); \
      vx[p4 * 4 + 0] = v.x; vx[p4 * 4 + 1] = v.y;                             \
      vx[p4 * 4 + 2] = v.z; vx[p4 * 4 + 3] = v.w;                             \
    }                                                                         \
  }

#define G_CVTWR(BUF)                                                          \
  {                                                                           \
    _Pragma("unroll")                                                         \
    for (int p4 = 0; p4 < 4; ++p4) {                                          \
      const int c_ = p4 * 64 + crow;                                          \
      sum4[p4] += (vx[p4 * 4 + 0] + vx[p4 * 4 + 1])                           \
                + (vx[p4 * 4 + 2] + vx[p4 * 4 + 3]);                          \
      u16x4 h;                                                                \
      h.x = f2bf(vx[p4 * 4 + 0]); h.y = f2bf(vx[p4 * 4 + 1]);                 \
      h.z = f2bf(vx[p4 * 4 + 2]); h.w = f2bf(vx[p4 * 4 + 3]);                 \
      *(u16x4*)(&lds[BUF][0] + ((c_ * 64 + sg * 4) ^ ((c_ & 7) << 3))) = h;   \
    }                                                                         \
  }

  G_LOADS(start);
  G_CVTWR(0);
  __syncthreads();

  for (int ch = start; ch < end; ++ch) {
    const int cur = (ch - start) & 1;
    if (ch + 1 < end) G_LOADS(ch + 1);
    const unsigned short* tile = &lds[cur][0];
#pragma unroll
    for (int kk = 0; kk < 64; kk += 32) {
      const s16x8 fw = *(const s16x8*)(tile + (((w * 16 + a) * 64 + kk + g * 8) ^ swzA));
#pragma unroll
      for (int j = 0; j < 16; ++j) {
        const s16x8 fj = *(const s16x8*)(tile + (((j * 16 + a) * 64 + kk + g * 8) ^ swzA));
        acc[j] = __builtin_amdgcn_mfma_f32_16x16x32_bf16(fw, fj, acc[j], 0, 0, 0);
      }
    }
    if (ch + 1 < end) G_CVTWR(cur ^ 1);
    __syncthreads();
  }
#undef G_LOADS
#undef G_CVTWR

  // ---- write partial Gram: D layout col=lane&15, row=(lane>>4)*4+reg ----
  float* gout = Gp + (long)p * 65536;
#pragma unroll
  for (int j = 0; j < 16; ++j)
#pragma unroll
    for (int r = 0; r < 4; ++r)
      gout[(16 * w + 4 * g + r) * 256 + 16 * j + a] = acc[j][r];

  // ---- channel sums: reduce over the 16 sg-lanes, atomic per (p4,w,g) ----
#pragma unroll
  for (int p4 = 0; p4 < 4; ++p4) {
    float s = sum4[p4];
    s += __shfl_xor(s, 1);
    s += __shfl_xor(s, 2);
    s += __shfl_xor(s, 4);
    s += __shfl_xor(s, 8);
    if (a == 0) atomicAdd(&meansum[p4 * 64 + w * 4 + g], s);
  }
}

// ---------------------------------------------------------------------------
// Kernel 2: reduce partials -> Sigma row per block; P0 = I; trace atomic.
// ---------------------------------------------------------------------------
__global__ __launch_bounds__(1024) void k_reduce(const float* __restrict__ Gp,
                                                 const float* __restrict__ meansum,
                                                 float* __restrict__ Sigma,
                                                 float* __restrict__ P0,
                                                 float* __restrict__ scal,
                                                 int nparts) {
  __shared__ float red[4][256];
  const int t = threadIdx.x, c = t & 255, g = t >> 8, j = blockIdx.x;
  const long e = (long)j * 256 + c;
  const int p0 = (nparts * g) >> 2, p1 = (nparts * (g + 1)) >> 2;
  const float* gp = Gp + (long)p0 * 65536 + e;
  const int np = p1 - p0;
  float s0 = 0.f, s1 = 0.f, s2 = 0.f, s3 = 0.f;
  int p = 0;
#pragma unroll 2
  for (; p + 4 <= np; p += 4) {
    s0 += gp[(long)(p + 0) * 65536];
    s1 += gp[(long)(p + 1) * 65536];
    s2 += gp[(long)(p + 2) * 65536];
    s3 += gp[(long)(p + 3) * 65536];
  }
  for (; p < np; ++p) s0 += gp[(long)p * 65536];
  red[g][c] = (s0 + s1) + (s2 + s3);
  __syncthreads();
  if (g == 0) {
    const float tot = red[0][c] + red[1][c] + red[2][c] + red[3][c];
    const float mc = meansum[c] * INV_M;
    const float mj = meansum[j] * INV_M;
    const float sig = tot * INV_M - mj * mc + ((j == c) ? EPSc : 0.f);
    Sigma[e] = sig;
    if (c == j) atomicAdd(scal, sig);
  } else if (g == 1) {
    P0[e] = (j == c) ? 1.f : 0.f;
  }
}

// ---------------------------------------------------------------------------
// Kernel 3 (x10): one Newton-Schulz step, fp32.
// 64 blocks x 1024 threads: 4 rows/block, 256 cols, split-K x4.
// ---------------------------------------------------------------------------
__global__ __launch_bounds__(1024) void k_ns(const float* __restrict__ Ps,
                                             float* __restrict__ Pd,
                                             const float* __restrict__ Sig,
                                             const float* __restrict__ scal) {
  __shared__ __align__(16) float PT[256][4];       // A-panel transposed [k][r]
  __shared__ __align__(16) float red[4][256][4];   // [kh][c][r]
  const int t = threadIdx.x, c = t & 255, kh = t >> 8, k0 = kh * 64;
  const int r0 = blockIdx.x * 4;

  PT[c][kh] = Ps[(r0 + kh) * 256 + c];
  __syncthreads();

  f32x4 acc;

#define NS_PHASE(BPTR)                                                        \
  {                                                                           \
    acc = (f32x4){0.f, 0.f, 0.f, 0.f};                                        \
    const float* Bb = (BPTR) + (long)k0 * 256 + c;                            \
    _Pragma("unroll 8")                                                       \
    for (int kk = 0; kk < 64; ++kk) {                                         \
      const float b = Bb[(long)kk * 256];                                     \
      const f32x4 a4 = *(const f32x4*)&PT[k0 + kk][0];                        \
      acc += a4 * b;                                                          \
    }                                                                         \
    *(f32x4*)&red[kh][c][0] = acc;                                            \
    __syncthreads();                                                          \
  }

#define NS_COMBINE()                                                          \
  {                                                                           \
    const f32x4 vs = (*(const f32x4*)&red[0][c][0] + *(const f32x4*)&red[1][c][0]) \
                   + (*(const f32x4*)&red[2][c][0] + *(const f32x4*)&red[3][c][0]); \
    if (kh == 0) *(f32x4*)&PT[c][0] = vs;                                     \
    __syncthreads();                                                          \
  }

  NS_PHASE(Ps);    // t1 = panel(P) * P
  NS_COMBINE();
  NS_PHASE(Ps);    // t2 = t1 * P
  NS_COMBINE();
  NS_PHASE(Sig);   // t3 = t2 * Sigma

  const float rTr = 1.0f / scal[0];
  const float t3 = ((red[0][c][kh] + red[1][c][kh]) + (red[2][c][kh] + red[3][c][kh]));
  const float pr = Ps[(r0 + kh) * 256 + c];
  Pd[(r0 + kh) * 256 + c] = 1.5f * pr - 0.5f * rTr * t3;
#undef NS_PHASE
#undef NS_COMBINE
}

// ---------------------------------------------------------------------------
// Kernel 4: A = sqrt(rTr) * (rot * P) -> bf16; bias = A * mean.
// ---------------------------------------------------------------------------
__global__ void k_makeA(const float* __restrict__ rot, const float* __restrict__ P,
                        const float* __restrict__ scal, const float* __restrict__ meansum,
                        unsigned short* __restrict__ Abf, float* __restrict__ bias) {
  __shared__ float Rw[8][256];
  __shared__ float Tw[8][256];
  const int r0 = blockIdx.x * 8, c = threadIdx.x;
#pragma unroll
  for (int r = 0; r < 8; ++r) Rw[r][c] = rot[(r0 + r) * 256 + c];
  __syncthreads();
  float t[8];
#pragma unroll
  for (int r = 0; r < 8; ++r) t[r] = 0.f;
  for (int k = 0; k < 256; ++k) {
    const float pv = P[k * 256 + c];
#pragma unroll
    for (int r = 0; r < 8; ++r) t[r] += Rw[r][k] * pv;
  }
  const float s = sqrtf(1.0f / scal[0]);
  const float mc = meansum[c] * INV_M;
#pragma unroll
  for (int r = 0; r < 8; ++r) {
    const float av = t[r] * s;
    Abf[(r0 + r) * 256 + c] = f2bf(av);
    Tw[r][c] = av * mc;
  }
  __syncthreads();
  for (int st = 128; st > 0; st >>= 1) {
    if (c < st) {
#pragma unroll
      for (int r = 0; r < 8; ++r) Tw[r][c] += Tw[r][c + st];
    }
    __syncthreads();
  }
  if (c == 0) {
#pragma unroll
    for (int r = 0; r < 8; ++r) bias[r0 + r] = Tw[r][0];
  }
}

// ---------------------------------------------------------------------------
// Kernel 5: out = A*x - bias. 512 blocks (64 b x 8 strips of 6-7 chunks).
// Swapped MFMA operands -> D rows = s -> float4 stores. A-frags in regs.
// Double-buffered LDS, T14 split staging.
// ---------------------------------------------------------------------------
__global__ __launch_bounds__(1024) void k_apply(const float* __restrict__ X,
                                                const unsigned short* __restrict__ Abf,
                                                const float* __restrict__ bias,
                                                float* __restrict__ out) {
  __shared__ __align__(16) unsigned short lds[2][64 * 256];
  const int t = threadIdx.x, w = t >> 6, l = t & 63, a = l & 15, g = l >> 4;
  const int bid = blockIdx.x;
  const int b = bid >> 3, strip = bid & 7;
  const int ch0 = (49 * strip) >> 3, ch1 = (49 * (strip + 1)) >> 3;

  // hoist A fragments (B-operand) + bias into registers
  const int d = 16 * w + a;
  s16x8 af[8];
#pragma unroll
  for (int kk8 = 0; kk8 < 8; ++kk8)
    af[kk8] = *(const s16x8*)(Abf + d * 256 + kk8 * 32 + g * 8);
  const float bd = bias[d];

  const float* xbase = X + (long)b * Cn * HWn;
  float* obase = out + (long)b * Cn * HWn;
  float vx[16];

#define A_LOADS(CH)                                                           \
  {                                                                           \
    const int s0_ = (CH) * 64;                                                \
    _Pragma("unroll")                                                         \
    for (int p4 = 0; p4 < 4; ++p4) {                                          \
      const int c4_ = p4 * 16 + w;                                            \
      const float* xp_ = xbase + (long)(c4_ * 4) * HWn + s0_ + l;             \
      vx[p4 * 4 + 0] = xp_[0];                                                \
      vx[p4 * 4 + 1] = xp_[HWn];                                              \
      vx[p4 * 4 + 2] = xp_[2 * HWn];                                          \
      vx[p4 * 4 + 3] = xp_[3 * HWn];                                          \
    }                                                                         \
  }

#define A_CVTWR(BUF)                                                          \
  {                                                                           \
    _Pragma("unroll")                                                         \
    for (int p4 = 0; p4 < 4; ++p4) {                                          \
      const int c4_ = p4 * 16 + w;                                            \
      u16x4 h;                                                                \
      h.x = f2bf(vx[p4 * 4 + 0]); h.y = f2bf(vx[p4 * 4 + 1]);                 \
      h.z = f2bf(vx[p4 * 4 + 2]); h.w = f2bf(vx[p4 * 4 + 3]);                 \
      *(u16x4*)(&lds[BUF][0] + ((l * 256 + c4_ * 4) ^ ((l & 7) << 3))) = h;   \
    }                                                                         \
  }

  A_LOADS(ch0);
  A_CVTWR(0);
  __syncthreads();

  for (int ch = ch0; ch < ch1; ++ch) {
    const int cur = (ch - ch0) & 1;
    if (ch + 1 < ch1) A_LOADS(ch + 1);

    const unsigned short* tile = &lds[cur][0];
    f32x4 acc[4];
#pragma unroll
    for (int st = 0; st < 4; ++st) acc[st] = (f32x4){0.f, 0.f, 0.f, 0.f};
#pragma unroll
    for (int kk8 = 0; kk8 < 8; ++kk8) {
#pragma unroll
      for (int st = 0; st < 4; ++st) {
        const s16x8 xf = *(const s16x8*)(tile + (((st * 16 + a) * 256 + kk8 * 32 + g * 8) ^ ((a & 7) << 3)));
        acc[st] = __builtin_amdgcn_mfma_f32_16x16x32_bf16(xf, af[kk8], acc[st], 0, 0, 0);
      }
    }
    // store: lane (a,g) holds s = st*16 + 4g + r  -> float4 per st
    const int s0 = ch * 64;
#pragma unroll
    for (int st = 0; st < 4; ++st) {
      const f32x4 o = acc[st] - bd;
      *(f32x4*)(obase + (long)d * HWn + s0 + st * 16 + 4 * g) = o;
    }

    if (ch + 1 < ch1) A_CVTWR(cur ^ 1);
    __syncthreads();
  }
#undef A_LOADS
#undef A_CVTWR
}

// ---------------------------------------------------------------------------
extern "C" void kernel_launch(void* const* d_in, const int* in_sizes, int n_in,
                              void* d_out, int out_size, void* d_ws, size_t ws_size,
                              hipStream_t stream) {
  const float* X = (const float*)d_in[0];
  const float* rot = (const float*)d_in[1];
  float* out = (float*)d_out;

  auto need = [](int np) -> size_t {
    return (size_t)4 * ((size_t)np * 65536 + 3 * 65536 + 256 + 16 + 256)
         + (size_t)2 * 65536;
  };
  int nparts = 256;
  while (nparts > 4 && need(nparts) > ws_size) nparts >>= 1;

  float* w = (float*)d_ws;
  float* Gp = w;       w += (size_t)nparts * 65536;
  float* Sigma = w;    w += 65536;
  float* P0 = w;       w += 65536;
  float* P1 = w;       w += 65536;
  float* meansum = w;  w += 256;
  float* scal = w;     w += 16;
  float* bias = w;     w += 256;
  unsigned short* Abf = (unsigned short*)w;

  hipMemsetAsync(meansum, 0, (256 + 16) * sizeof(float), stream);

  k_gram<<<dim3(nparts), dim3(1024), 0, stream>>>(X, Gp, meansum, nparts);
  k_reduce<<<dim3(256), dim3(1024), 0, stream>>>(Gp, meansum, Sigma, P0, scal, nparts);
  float* ps = P0;
  float* pd = P1;
  for (int i = 0; i < 10; ++i) {
    k_ns<<<dim3(64), dim3(1024), 0, stream>>>(ps, pd, Sigma, scal);
    float* tmp = ps; ps = pd; pd = tmp;
  }
  k_makeA<<<dim3(32), dim3(256), 0, stream>>>(rot, ps, scal, meansum, Abf, bias);
  k_apply<<<dim3(512), dim3(1024), 0, stream>>>(X, Abf, bias, out);
}